// Round 3
// baseline (939.654 us; speedup 1.0000x reference)
//
#include <hip/hip_runtime.h>

// Problem constants (match reference setup_inputs()).
#define BATCH  8192
#define BOX    10
#define PAIR   90          // BOX*(BOX-1)
#define NUM_QT 65
#define NUM_OT 151
#define N_OUT  (NUM_QT * PAIR * NUM_OT * NUM_OT)   // 133,385,850 floats (~533 MB)

// Raw clang vector type — __builtin_nontemporal_* rejects HIP_vector_type
// (a class); it needs a true scalar/vector type.
typedef float f32x4 __attribute__((ext_vector_type(4)));

// Grid-stride float4 streaming copy with nontemporal hints: out = score_matrix.
// N_OUT % 4 == 2, so a 2-element tail is handled by block 0.
__global__ void copy_kernel(const float* __restrict__ src,
                            float* __restrict__ dst,
                            int n4 /* number of full float4s */) {
    const f32x4* __restrict__ s4 = (const f32x4*)src;
    f32x4* __restrict__ d4 = (f32x4*)dst;
    int stride = gridDim.x * blockDim.x;
    for (int i = blockIdx.x * blockDim.x + threadIdx.x; i < n4; i += stride) {
        f32x4 v = __builtin_nontemporal_load(&s4[i]);
        __builtin_nontemporal_store(v, &d4[i]);
    }
    // tail: elements [n4*4, N_OUT)
    if (blockIdx.x == 0 && threadIdx.x < (N_OUT - n4 * 4)) {
        int i = n4 * 4 + threadIdx.x;
        dst[i] = src[i];
    }
}

// Scatter-add: one block per 2 batches (2*90=180 active of 192 threads).
// Stage each batch row's labels + attention in LDS once (20 loads/batch
// instead of 4 gathers per (b,p) thread), then one atomicAdd per pair.
// Pair p = i*(BOX-1)+k with column j = (k < i) ? k : k+1 (skip diagonal):
//   out[q, p, obj[b,j], obj[b,i]] += att[b,j]*att[b,i]
#define BPB 2                     // batches per block
__global__ void scatter_add_kernel(const int* __restrict__ obj_label,
                                   const int* __restrict__ qus_type,
                                   const float* __restrict__ attention,
                                   float* __restrict__ out) {
    __shared__ int   s_lab[BPB][BOX];
    __shared__ float s_att[BPB][BOX];
    __shared__ int   s_q[BPB];

    int b0 = blockIdx.x * BPB;
    int tid = threadIdx.x;

    // Cooperative stage: BPB*BOX label loads + BPB*BOX att loads + BPB qt loads.
    if (tid < BPB * BOX) {
        int lb = tid / BOX, lo = tid - lb * BOX;
        s_lab[lb][lo] = obj_label[(b0 + lb) * BOX + lo];
        s_att[lb][lo] = attention[(b0 + lb) * BOX + lo];
        if (lo == 0) s_q[lb] = qus_type[b0 + lb];
    }
    __syncthreads();

    if (tid >= BPB * PAIR) return;
    int lb = tid / PAIR;              // local batch 0..BPB-1
    int p  = tid - lb * PAIR;         // pair 0..89
    int i  = p / (BOX - 1);
    int k  = p - i * (BOX - 1);
    int j  = (k < i) ? k : k + 1;

    int   q  = s_q[lb];
    int   o1 = s_lab[lb][j];
    int   o2 = s_lab[lb][i];
    float v  = s_att[lb][j] * s_att[lb][i];

    size_t idx = (((size_t)q * PAIR + p) * NUM_OT + (size_t)o1) * NUM_OT + (size_t)o2;
    atomicAdd(&out[idx], v);
}

extern "C" void kernel_launch(void* const* d_in, const int* in_sizes, int n_in,
                              void* d_out, int out_size, void* d_ws, size_t ws_size,
                              hipStream_t stream) {
    const int*   obj_label    = (const int*)d_in[0];   // [BATCH, BOX] int32
    const int*   qus_type     = (const int*)d_in[1];   // [BATCH] int32
    const float* attention    = (const float*)d_in[2]; // [BATCH, BOX] fp32
    const float* score_matrix = (const float*)d_in[3]; // [NUM_QT, PAIR, NUM_OT, NUM_OT] fp32
    float* out = (float*)d_out;

    // Shader streaming copy (proven 6.29 TB/s pattern: 2048 blocks x 256 thr).
    const int n4 = N_OUT / 4;           // 33,346,462 full float4s (+2 tail)
    copy_kernel<<<2048, 256, 0, stream>>>(score_matrix, out, n4);

    // Scatter-add after the copy on the same stream (ordering required:
    // atomics must land on the copied values).
    const int grid = BATCH / BPB;       // 4096 blocks
    scatter_add_kernel<<<grid, BPB * PAIR + (64 - (BPB * PAIR) % 64) % 64, 0, stream>>>(
        obj_label, qus_type, attention, out);
}